// Round 6
// baseline (141.867 us; speedup 1.0000x reference)
//
#include <hip/hip_runtime.h>
#include <hip/hip_bf16.h>

#define NTOT   8192
#define BHALF  4096
#define DDIM   256
#define SMOD   32     // column-strip stride; grid (32, SMOD)
#define NPART  4      // partial copies of s_part to spread atomic contention
#define MAXSLOT 6     // max strips per block (pair bound: <=5, +1 slack)
#define EXPSCALE 14.4269504088896341f   // 10 / ln(2): exp(10x) = exp2(EXPSCALE*x)

typedef __attribute__((ext_vector_type(8))) short bf16x8_t;  // 8 bf16 = 4 VGPRs
typedef __attribute__((ext_vector_type(4))) float f32x4_t;   // MFMA C/D

__device__ inline unsigned short f2bf(float x) {
    __hip_bfloat16 h = __float2bfloat16(x);
    return __builtin_bit_cast(unsigned short, h);
}

// ---- kernel 1: normalize pair k (rows k, k+B) -> bf16 zn; posdot; zero s_part ----
__global__ void norm_pair_kernel(const float* __restrict__ zi,
                                 const float* __restrict__ zj,
                                 unsigned short* __restrict__ zn,
                                 float* __restrict__ posdot,
                                 float* __restrict__ s_part) {
    int gtid = blockIdx.x * 256 + threadIdx.x;
    if (gtid < NTOT * NPART) s_part[gtid] = 0.0f;   // done before gemm (stream order)
    int k    = gtid >> 6;
    int lane = gtid & 63;
    float4 vi = reinterpret_cast<const float4*>(zi + (size_t)k * DDIM)[lane];
    float4 vj = reinterpret_cast<const float4*>(zj + (size_t)k * DDIM)[lane];
    float ssi = vi.x*vi.x + vi.y*vi.y + vi.z*vi.z + vi.w*vi.w;
    float ssj = vj.x*vj.x + vj.y*vj.y + vj.z*vj.z + vj.w*vj.w;
    float dot = vi.x*vj.x + vi.y*vj.y + vi.z*vj.z + vi.w*vj.w;
    #pragma unroll
    for (int off = 32; off >= 1; off >>= 1) {
        ssi += __shfl_xor(ssi, off);
        ssj += __shfl_xor(ssj, off);
        dot += __shfl_xor(dot, off);
    }
    float ri = 1.0f / fmaxf(sqrtf(ssi), 1e-8f);
    float rj = 1.0f / fmaxf(sqrtf(ssj), 1e-8f);
    ushort4 oi, oj;
    oi.x = f2bf(vi.x * ri); oi.y = f2bf(vi.y * ri);
    oi.z = f2bf(vi.z * ri); oi.w = f2bf(vi.w * ri);
    oj.x = f2bf(vj.x * rj); oj.y = f2bf(vj.y * rj);
    oj.z = f2bf(vj.z * rj); oj.w = f2bf(vj.w * rj);
    reinterpret_cast<ushort4*>(zn + (size_t)k * DDIM)[lane] = oi;
    reinterpret_cast<ushort4*>(zn + (size_t)(k + BHALF) * DDIM)[lane] = oj;
    if (lane == 0) posdot[k] = dot * ri * rj * 10.0f;
}

// ---- kernel 2: symmetric fused GEMM + exp-sum, v7: 4 independent blocks/CU ----
// History: v1 sync-stage 45.6 | v2 async-dbuf 45.6 | v3 8-wave 48.5 | v4/v5
// reg-stream 74-80 | v6 phase-split ~43. Barrier count, prefetch depth, and
// within-block pacing are all non-levers; pipes sum to <40% busy. Every
// variant had exactly 2 independent barrier domains (blocks) per CU. v7 makes
// it 4: LDS 38 KB (single 32KB B-buffer -- dbuf proved worthless -- + 6KB
// colLDS), SMOD=32 -> grid (32,32) = 1024 blocks a 4-6 strips. Same total
// LDS/MFMA/VALU work, same swizzles/staging; but 4 de-correlated convoys per
// CU: one block's ds_read/MFMA runs under another's stage/vmcnt/barrier stall.
// __launch_bounds__(256,4) caps VGPR at 128 (afrag remat per strip: v2 lived
// with it). Pairing (bi, 63-bi) bounds strips/block at 5 (MAXSLOT=6).
__global__ void __launch_bounds__(256, 4)
gemm_sym_kernel(const unsigned short* __restrict__ zn,
                float* __restrict__ s_part) {
    __shared__ unsigned short ldsB[64 * 256];      // 32 KB, single buffer
    __shared__ float colLDS[MAXSLOT][4][64];       // 6 KB
    // total 38 KB -> 4 blocks/CU = 16 waves/CU, 4 independent barrier domains

    const int tid  = threadIdx.x;
    const int lane = tid & 63;
    const int wv   = tid >> 6;        // 0..3 -> 32-row slice of the 128-row block
    const int m    = lane & 15;
    const int quad = lane >> 4;
    const int biA  = blockIdx.x;      // 0..31
    const int s    = blockIdx.y;      // 0..31

    float* rowPart = s_part + (size_t)(s   & (NPART - 1)) * NTOT;
    float* colPart = s_part + (size_t)(biA & (NPART - 1)) * NTOT;

    int slot = 0;
    #pragma unroll
    for (int p = 0; p < 2; ++p) {
        const int bi = p ? (63 - biA) : biA;
        const int R0 = bi << 7;
        const int cs0 = 2 * bi + ((s - 2 * bi) & (SMOD - 1));
        if (cs0 >= 128) continue;     // block-uniform: no divergence hazard

        // A fragments: rows R0 + wv*32 + rf*16 + m, k = kk*32 + quad*8 (+j)
        bf16x8_t afrag[2][8];
        #pragma unroll
        for (int rf = 0; rf < 2; ++rf) {
            const unsigned short* arow = zn + (size_t)(R0 + wv*32 + rf*16 + m) * DDIM;
            #pragma unroll
            for (int kk = 0; kk < 8; ++kk)
                afrag[rf][kk] = *reinterpret_cast<const bf16x8_t*>(arow + kk*32 + quad*8);
        }

        float rowacc[2][4] = {{0.f,0.f,0.f,0.f},{0.f,0.f,0.f,0.f}};

        for (int cs = cs0; cs < 128; cs += SMOD) {
            const int C0 = cs << 6;
            const bool isDiag = ((cs >> 1) == bi);

            __syncthreads();   // previous strip's ldsB readers done
            // stage B tile 64 rows x 256 k via global_load_lds width=16:
            // LDS dest linear (gl_lds rule), xor-swizzle on the GLOBAL source
            // chunk index (both-sides rule, m104/m231)
            #pragma unroll
            for (int t = 0; t < 8; ++t) {
                int ci = t * 256 + tid;
                int r = ci >> 5, c = ci & 31;
                const unsigned short* g =
                    zn + (size_t)(C0 + r) * DDIM + ((c ^ (r & 7)) << 3);
                __builtin_amdgcn_global_load_lds(
                    (const __attribute__((address_space(1))) unsigned int*)g,
                    (__attribute__((address_space(3))) unsigned int*)
                        &ldsB[(size_t)ci * 8],
                    16, 0, 0);
            }
            __syncthreads();   // drains vmcnt -> staging visible to all waves

            #pragma unroll
            for (int cf = 0; cf < 4; ++cf) {
                f32x4_t c0 = (f32x4_t){0.f,0.f,0.f,0.f};
                f32x4_t c1 = (f32x4_t){0.f,0.f,0.f,0.f};
                #pragma unroll
                for (int kk = 0; kk < 8; ++kk) {
                    bf16x8_t b = *reinterpret_cast<const bf16x8_t*>(
                        &ldsB[(cf*16 + m) * 256 + (((kk*4 + quad) ^ (m & 7)) << 3)]);
                    c0 = __builtin_amdgcn_mfma_f32_16x16x32_bf16(afrag[0][kk], b, c0, 0, 0, 0);
                    c1 = __builtin_amdgcn_mfma_f32_16x16x32_bf16(afrag[1][kk], b, c1, 0, 0, 0);
                }
                const int gc = C0 + cf*16 + m;
                float colsum = 0.f;
                #pragma unroll
                for (int r = 0; r < 4; ++r) {
                    int gr0 = R0 + wv*32 + quad*4 + r;
                    float e0 = exp2f(c0[r] * EXPSCALE);
                    float e1 = exp2f(c1[r] * EXPSCALE);
                    if (isDiag && gr0 == gc)        e0 = 0.f;
                    if (isDiag && (gr0 + 16) == gc) e1 = 0.f;
                    rowacc[0][r] += e0;
                    rowacc[1][r] += e1;
                    colsum += e0 + e1;
                }
                if (!isDiag) {
                    // reduce over the 64 rows this wave covers (quad lanes)
                    colsum += __shfl_xor(colsum, 16);
                    colsum += __shfl_xor(colsum, 32);
                    if (quad == 0) colLDS[slot][wv][cf*16 + m] = colsum;
                }
            }
            ++slot;
        }

        // row totals for this phase: reduce over 16 m-lanes, one atomic per row
        #pragma unroll
        for (int rf = 0; rf < 2; ++rf)
            #pragma unroll
            for (int r = 0; r < 4; ++r) {
                float v = rowacc[rf][r];
                v += __shfl_xor(v, 1);
                v += __shfl_xor(v, 2);
                v += __shfl_xor(v, 4);
                v += __shfl_xor(v, 8);
                if (m == 0)
                    atomicAdd(&rowPart[R0 + wv*32 + rf*16 + quad*4 + r], v);
            }
    }

    __syncthreads();   // all colLDS writes complete

    // flush column sums: re-enumerate strips in the same order
    if (tid < 64) {
        int slot2 = 0;
        #pragma unroll
        for (int p = 0; p < 2; ++p) {
            const int bi = p ? (63 - biA) : biA;
            const int cs0 = 2 * bi + ((s - 2 * bi) & (SMOD - 1));
            if (cs0 >= 128) continue;
            for (int cs = cs0; cs < 128; cs += SMOD) {
                if ((cs >> 1) != bi) {
                    float v = colLDS[slot2][0][tid] + colLDS[slot2][1][tid]
                            + colLDS[slot2][2][tid] + colLDS[slot2][3][tid];
                    atomicAdd(&colPart[(cs << 6) + tid], v);
                }
                ++slot2;
            }
        }
    }
}

// ---- kernel 3: loss_k = log(sum_p s_part[p][k]) - posdot[k%B]; masked mean ----
__global__ void finalize_kernel(const float* __restrict__ s_part,
                                const float* __restrict__ posdot,
                                const unsigned char* __restrict__ mask,
                                float* __restrict__ out) {
    int tid = threadIdx.x, lane = tid & 63, wv = tid >> 6;
    float tot = 0.f, cnt = 0.f;
    #pragma unroll
    for (int si = 0; si < NTOT / 1024; ++si) {
        int k = si * 1024 + tid;
        int kb = k & (BHALF - 1);
        if (mask[kb] != 0) {
            float sk = s_part[k] + s_part[NTOT + k]
                     + s_part[2*NTOT + k] + s_part[3*NTOT + k];
            tot += __logf(sk) - posdot[kb];
            cnt += 1.f;
        }
    }
    #pragma unroll
    for (int off = 32; off >= 1; off >>= 1) {
        tot += __shfl_xor(tot, off);
        cnt += __shfl_xor(cnt, off);
    }
    __shared__ float st[16], sc[16];
    if (lane == 0) { st[wv] = tot; sc[wv] = cnt; }
    __syncthreads();
    if (tid == 0) {
        float T = 0.f, C = 0.f;
        #pragma unroll
        for (int i = 0; i < 16; ++i) { T += st[i]; C += sc[i]; }
        out[0] = (C > 0.f) ? (T / fmaxf(C, 1.f)) : 0.f;
    }
}

extern "C" void kernel_launch(void* const* d_in, const int* in_sizes, int n_in,
                              void* d_out, int out_size, void* d_ws, size_t ws_size,
                              hipStream_t stream) {
    const float* zi = (const float*)d_in[0];
    const float* zj = (const float*)d_in[1];
    const unsigned char* mask = (const unsigned char*)d_in[2];
    float* out = (float*)d_out;

    // ws: [0,4MB) zn bf16; s_part[NPART][8192] f32; posdot[4096] f32
    unsigned short* zn = (unsigned short*)d_ws;
    float* s_part = (float*)((char*)d_ws + (size_t)NTOT * DDIM * 2);
    float* posdot = s_part + NPART * NTOT;

    norm_pair_kernel<<<dim3(1024), dim3(256), 0, stream>>>(zi, zj, zn, posdot, s_part);
    gemm_sym_kernel<<<dim3(32, SMOD), dim3(256), 0, stream>>>(zn, s_part);
    finalize_kernel<<<dim3(1), dim3(1024), 0, stream>>>(s_part, posdot, mask, out);
}

// Round 7
// 119.686 us; speedup vs baseline: 1.1853x; 1.1853x over previous
//
#include <hip/hip_runtime.h>
#include <hip/hip_bf16.h>

#define NTOT   8192
#define BHALF  4096
#define DDIM   256
#define NPART  4      // partial copies of s_part to spread atomic contention
#define MAXSLOT 18    // max strips per wave: 16 (phase0, p=0) + 1..2 (phase1)
#define EXPSCALE 14.4269504088896341f   // 10 / ln(2): exp(10x) = exp2(EXPSCALE*x)

typedef __attribute__((ext_vector_type(8))) short bf16x8_t;  // 8 bf16 = 4 VGPRs
typedef __attribute__((ext_vector_type(4))) float f32x4_t;   // MFMA C/D

__device__ inline unsigned short f2bf(float x) {
    __hip_bfloat16 h = __float2bfloat16(x);
    return __builtin_bit_cast(unsigned short, h);
}

// ---- kernel 1: normalize pair k (rows k, k+B) -> bf16 zn; posdot; zero s_part ----
__global__ void norm_pair_kernel(const float* __restrict__ zi,
                                 const float* __restrict__ zj,
                                 unsigned short* __restrict__ zn,
                                 float* __restrict__ posdot,
                                 float* __restrict__ s_part) {
    int gtid = blockIdx.x * 256 + threadIdx.x;
    if (gtid < NTOT * NPART) s_part[gtid] = 0.0f;   // done before gemm (stream order)
    int k    = gtid >> 6;
    int lane = gtid & 63;
    float4 vi = reinterpret_cast<const float4*>(zi + (size_t)k * DDIM)[lane];
    float4 vj = reinterpret_cast<const float4*>(zj + (size_t)k * DDIM)[lane];
    float ssi = vi.x*vi.x + vi.y*vi.y + vi.z*vi.z + vi.w*vi.w;
    float ssj = vj.x*vj.x + vj.y*vj.y + vj.z*vj.z + vj.w*vj.w;
    float dot = vi.x*vj.x + vi.y*vj.y + vi.z*vj.z + vi.w*vj.w;
    #pragma unroll
    for (int off = 32; off >= 1; off >>= 1) {
        ssi += __shfl_xor(ssi, off);
        ssj += __shfl_xor(ssj, off);
        dot += __shfl_xor(dot, off);
    }
    float ri = 1.0f / fmaxf(sqrtf(ssi), 1e-8f);
    float rj = 1.0f / fmaxf(sqrtf(ssj), 1e-8f);
    ushort4 oi, oj;
    oi.x = f2bf(vi.x * ri); oi.y = f2bf(vi.y * ri);
    oi.z = f2bf(vi.z * ri); oi.w = f2bf(vi.w * ri);
    oj.x = f2bf(vj.x * rj); oj.y = f2bf(vj.y * rj);
    oj.z = f2bf(vj.z * rj); oj.w = f2bf(vj.w * rj);
    reinterpret_cast<ushort4*>(zn + (size_t)k * DDIM)[lane] = oi;
    reinterpret_cast<ushort4*>(zn + (size_t)(k + BHALF) * DDIM)[lane] = oj;
    if (lane == 0) posdot[k] = dot * ri * rj * 10.0f;
}

// ---- kernel 2: symmetric fused GEMM + exp-sum, v8: 1-wave blocks, 0 barriers ----
// v1-v7 invariant: ~43-46us whenever the 4-wave barrier-domain survives; all
// pipes <35%; occupancy-raising attempts died to allocator pathologies (v7:
// launch_bounds min -> VGPR 64 + 73MB scratch spills). v8: barrier domain =
// ONE wave. 64-thread blocks, 16/CU (amdgpu_waves_per_eu(4,4) pins the 128-reg
// budget; opaque-asm pins A liveness -- the v5 combo that held VGPR=100).
// Wave owns a 32-row tile (A resident, 64 VGPR, K=256), stages its own
// 16col x 128K B-subtile (4KB) into a private LDS dbuf via 4 global_load_lds,
// pipelined with counted vmcnt(4) -- never 0 mid-loop, NO s_barrier anywhere.
// Colsums buffered in LDS, rowsums in regs -> no atomics in the loop (v5's
// vmcnt-poison fixed). Upper-tri decomposition at 32x16 granularity: tile
// (R, s) for s >= 2R; diag strips (s>>1 == R) keep only gc > gr; every kept
// cell adds to rowsum[gr] and (mirror) colsum[gc]. (p, 255-p) pairing + 32-way
// residue striding balances waves at 16-17 strips. 4096 waves = exactly 16/CU.
__global__ void __attribute__((amdgpu_flat_work_group_size(64, 64),
                               amdgpu_waves_per_eu(4, 4)))
gemm_sym_kernel(const unsigned short* __restrict__ zn,
                float* __restrict__ s_part) {
    __shared__ unsigned short ldsA[2048];   // 4 KB stage buffer (h=0 halves)
    __shared__ unsigned short ldsB[2048];   // 4 KB stage buffer (h=1 halves)
    __shared__ float colLDS[MAXSLOT][16];   // 1.1 KB -> 9.3 KB total, 16 blk/CU

    const int lane = threadIdx.x;           // 0..63 (one wave)
    const int m    = lane & 15;
    const int quad = lane >> 4;
    const int wid  = blockIdx.x;            // 0..4095
    const int p    = wid >> 5;              // pair index 0..127
    const int j    = wid & 31;              // residue lane 0..31

    float* rowPart = s_part + (size_t)(j & (NPART - 1)) * NTOT;
    float* colPart = s_part + (size_t)(p & (NPART - 1)) * NTOT;

// stage 16 cols x 128 K (half hV) of strip sV: 4 gl_lds x 16B/lane. LDS dest
// linear (gl_lds rule); xor-swizzle on the GLOBAL source chunk (both-sides).
#define STAGE(dst, sV, hV) {                                                  \
    _Pragma("unroll")                                                         \
    for (int t_ = 0; t_ < 4; ++t_) {                                          \
        int ci_ = t_ * 64 + lane;                                             \
        int r_ = ci_ >> 4, c_ = ci_ & 15;                                     \
        const unsigned short* g_ = zn + (size_t)((sV) * 16 + r_) * DDIM       \
                                   + (hV) * 128 + ((c_ ^ (r_ & 7)) << 3);     \
        __builtin_amdgcn_global_load_lds(                                     \
            (const __attribute__((address_space(1))) unsigned int*)g_,        \
            (__attribute__((address_space(3))) unsigned int*)((dst) + ci_*8), \
            16, 0, 0);                                                        \
    } }

// 4 ds_read_b128 + 8 MFMA for half hV (k-chunks hV*4 .. hV*4+3)
#define HALF(buf, hV) {                                                       \
    bf16x8_t bfr[4];                                                          \
    _Pragma("unroll")                                                         \
    for (int kk_ = 0; kk_ < 4; ++kk_)                                         \
        bfr[kk_] = *reinterpret_cast<const bf16x8_t*>(                        \
            (buf) + m * 128 + ((((kk_ << 2) + quad) ^ (m & 7)) << 3));        \
    _Pragma("unroll")                                                         \
    for (int kk_ = 0; kk_ < 4; ++kk_) {                                       \
        acc0 = __builtin_amdgcn_mfma_f32_16x16x32_bf16(                       \
                   afrag[0][(hV)*4 + kk_], bfr[kk_], acc0, 0, 0, 0);          \
        acc1 = __builtin_amdgcn_mfma_f32_16x16x32_bf16(                       \
                   afrag[1][(hV)*4 + kk_], bfr[kk_], acc1, 0, 0, 0);          \
    } }

    int slot = 0;
    #pragma unroll
    for (int ph = 0; ph < 2; ++ph) {
        const int R    = ph ? (255 - p) : p;    // 32-row tile index 0..255
        const int jj   = ph ? (31 - j) : j;     // anti-correlated residue
        const int smin = 2 * R;                 // first 16-col strip on/after diag
        int s = smin + ((jj - smin) & 31);      // first strip ≡ jj (mod 32)
        if (s >= 512) continue;                 // wave-uniform

        // A fragments: rows R*32 + rf*16 + m, k = kk*32 + quad*8 (+0..7)
        bf16x8_t afrag[2][8];
        #pragma unroll
        for (int rf = 0; rf < 2; ++rf) {
            const unsigned short* ap =
                zn + (size_t)((R << 5) + rf * 16 + m) * DDIM + quad * 8;
            #pragma unroll
            for (int kk = 0; kk < 8; ++kk)
                afrag[rf][kk] = *reinterpret_cast<const bf16x8_t*>(ap + kk * 32);
        }
        // opaque pass: forbid remat-from-memory (v4) and keep A live (v7)
        #pragma unroll
        for (int rf = 0; rf < 2; ++rf)
            #pragma unroll
            for (int kk = 0; kk < 8; ++kk) {
                int4 t_ = __builtin_bit_cast(int4, afrag[rf][kk]);
                asm volatile("" : "+v"(t_.x), "+v"(t_.y), "+v"(t_.z), "+v"(t_.w));
                afrag[rf][kk] = __builtin_bit_cast(bf16x8_t, t_);
            }

        float ra0[4] = {0.f, 0.f, 0.f, 0.f};
        float ra1[4] = {0.f, 0.f, 0.f, 0.f};

        // pipeline: ldsA always holds h=0 halves, ldsB h=1 (parity-locked)
        STAGE(ldsA, s, 0);
        for (;;) {
            STAGE(ldsB, s, 1);                       // next stage (always exists)
            asm volatile("s_waitcnt vmcnt(4)" ::: "memory");  // ldsA landed
            __builtin_amdgcn_sched_barrier(0);
            f32x4_t acc0 = (f32x4_t){0.f, 0.f, 0.f, 0.f};
            f32x4_t acc1 = (f32x4_t){0.f, 0.f, 0.f, 0.f};
            HALF(ldsA, 0);

            const bool more = (s + 32 < 512);        // wave-uniform
            if (more) { STAGE(ldsA, s + 32, 0); }
            if (more) { asm volatile("s_waitcnt vmcnt(4)" ::: "memory"); }
            else      { asm volatile("s_waitcnt vmcnt(0)" ::: "memory"); }
            __builtin_amdgcn_sched_barrier(0);
            HALF(ldsB, 1);

            // fused epilogue: e = exp(10*sim); diag strips keep only gc > gr
            {
                const int gc = s * 16 + m;
                const bool dg = ((s >> 1) == R);
                float colsum = 0.f;
                #pragma unroll
                for (int r = 0; r < 4; ++r) {
                    float e0 = exp2f(acc0[r] * EXPSCALE);
                    float e1 = exp2f(acc1[r] * EXPSCALE);
                    if (dg) {
                        int gr0 = (R << 5) + quad * 4 + r;
                        e0 = (gc > gr0)      ? e0 : 0.f;
                        e1 = (gc > gr0 + 16) ? e1 : 0.f;
                    }
                    ra0[r] += e0;
                    ra1[r] += e1;
                    colsum += e0 + e1;
                }
                colsum += __shfl_xor(colsum, 16);    // sum over the 32 rows
                colsum += __shfl_xor(colsum, 32);
                if (quad == 0) colLDS[slot][m] = colsum;
                ++slot;
            }
            if (!more) break;
            s += 32;
        }

        // row totals: reduce over 16 m-lanes, atomics once per phase
        #pragma unroll
        for (int r = 0; r < 4; ++r) {
            float v0 = ra0[r], v1 = ra1[r];
            v0 += __shfl_xor(v0, 1); v0 += __shfl_xor(v0, 2);
            v0 += __shfl_xor(v0, 4); v0 += __shfl_xor(v0, 8);
            v1 += __shfl_xor(v1, 1); v1 += __shfl_xor(v1, 2);
            v1 += __shfl_xor(v1, 4); v1 += __shfl_xor(v1, 8);
            if (m == 0) {
                atomicAdd(&rowPart[(R << 5) + quad * 4 + r], v0);
                atomicAdd(&rowPart[(R << 5) + 16 + quad * 4 + r], v1);
            }
        }
    }
#undef STAGE
#undef HALF

    // flush column sums: re-enumerate strips in the same order (single wave,
    // no barrier needed; compiler orders ds_write->ds_read via lgkmcnt)
    int slot2 = 0;
    #pragma unroll
    for (int ph = 0; ph < 2; ++ph) {
        const int R    = ph ? (255 - p) : p;
        const int jj   = ph ? (31 - j) : j;
        const int smin = 2 * R;
        int s = smin + ((jj - smin) & 31);
        for (; s < 512; s += 32) {
            float v = colLDS[slot2][m];
            if (quad == 0) atomicAdd(&colPart[s * 16 + m], v);
            ++slot2;
        }
    }
}

// ---- kernel 3: loss_k = log(sum_p s_part[p][k]) - posdot[k%B]; masked mean ----
__global__ void finalize_kernel(const float* __restrict__ s_part,
                                const float* __restrict__ posdot,
                                const unsigned char* __restrict__ mask,
                                float* __restrict__ out) {
    int tid = threadIdx.x, lane = tid & 63, wv = tid >> 6;
    float tot = 0.f, cnt = 0.f;
    #pragma unroll
    for (int si = 0; si < NTOT / 1024; ++si) {
        int k = si * 1024 + tid;
        int kb = k & (BHALF - 1);
        if (mask[kb] != 0) {
            float sk = s_part[k] + s_part[NTOT + k]
                     + s_part[2*NTOT + k] + s_part[3*NTOT + k];
            tot += __logf(sk) - posdot[kb];
            cnt += 1.f;
        }
    }
    #pragma unroll
    for (int off = 32; off >= 1; off >>= 1) {
        tot += __shfl_xor(tot, off);
        cnt += __shfl_xor(cnt, off);
    }
    __shared__ float st[16], sc[16];
    if (lane == 0) { st[wv] = tot; sc[wv] = cnt; }
    __syncthreads();
    if (tid == 0) {
        float T = 0.f, C = 0.f;
        #pragma unroll
        for (int i = 0; i < 16; ++i) { T += st[i]; C += sc[i]; }
        out[0] = (C > 0.f) ? (T / fmaxf(C, 1.f)) : 0.f;
    }
}

extern "C" void kernel_launch(void* const* d_in, const int* in_sizes, int n_in,
                              void* d_out, int out_size, void* d_ws, size_t ws_size,
                              hipStream_t stream) {
    const float* zi = (const float*)d_in[0];
    const float* zj = (const float*)d_in[1];
    const unsigned char* mask = (const unsigned char*)d_in[2];
    float* out = (float*)d_out;

    // ws: [0,4MB) zn bf16; s_part[NPART][8192] f32; posdot[4096] f32
    unsigned short* zn = (unsigned short*)d_ws;
    float* s_part = (float*)((char*)d_ws + (size_t)NTOT * DDIM * 2);
    float* posdot = s_part + NPART * NTOT;

    norm_pair_kernel<<<dim3(1024), dim3(256), 0, stream>>>(zi, zj, zn, posdot, s_part);
    gemm_sym_kernel<<<dim3(4096), dim3(64), 0, stream>>>(zn, s_part);
    finalize_kernel<<<dim3(1), dim3(1024), 0, stream>>>(s_part, posdot, mask, out);
}